// Round 1
// 194.595 us; speedup vs baseline: 1.0118x; 1.0118x over previous
//
#include <hip/hip_runtime.h>

#define Bb 4
#define Tt 64
#define Nn 16
#define Mm 8
#define Dd 512
#define RR 32      // Bb*Mm rows per (t,n) group
#define QSTR 520   // padded LDS row stride in u16 (1040 B: 16B-aligned, breaks pow2)

typedef __attribute__((ext_vector_type(8))) short bf16x8;
typedef __attribute__((ext_vector_type(16))) float f32x16;

__device__ __forceinline__ unsigned short f2bf(float f) {
    union { float f; unsigned int u; } v; v.f = f;
    unsigned int r = (v.u + 0x7fffu + ((v.u >> 16) & 1u)) >> 16;  // RNE
    return (unsigned short)r;
}
__device__ __forceinline__ float bf2f(unsigned short h) {
    union { unsigned int u; float f; } v; v.u = ((unsigned int)h) << 16;
    return v.f;
}

// Pack Wq|Wk|Wv (f32 [512,512], rows = output feature) into bf16 in 32x32 MFMA
// fragment order: Wb[((e*32+kk)*64 + hi*32 + n)*8 + j] = W[e*32+n][kk*16 + hi*8 + j]
// (e in [0,48): 0-15=Q,16-31=K,32-47=V)
// Output-driven: consecutive threads write consecutive ushort4 -> fully coalesced
// stores; gathered 16B reads stay within L2 (W is 3 MB).
__global__ __launch_bounds__(256) void convert_w_kernel(
    const float* __restrict__ Wq, const float* __restrict__ Wk,
    const float* __restrict__ Wv, unsigned short* __restrict__ Wb)
{
    int idx = blockIdx.x * 256 + threadIdx.x;   // ushort4 units; 196608 total
    int o = idx << 2;            // u16 index into Wb
    int j  = o & 7;              // 0 or 4
    int n  = (o >> 3) & 31;
    int hi = (o >> 8) & 1;
    int ekk = o >> 9;            // e*32+kk
    int kk = ekk & 31;
    int e  = ekk >> 5;           // 0..47
    int row = e * 32 + n;        // 0..1535
    int d = kk * 16 + hi * 8 + j;
    const float* src = (row < 512) ? Wq : ((row < 1024) ? Wk : Wv);
    int r = row & 511;
    float4 v = *(const float4*)(src + r * Dd + d);
    ushort4 o4;
    o4.x = f2bf(v.x); o4.y = f2bf(v.y); o4.z = f2bf(v.z); o4.w = f2bf(v.w);
    *(ushort4*)(Wb + o) = o4;
}

// One block per TWO (t,n) groups (same t, n0 and n0+1). 1024 threads = 16 waves.
// Wave w owns feature tile [32w,32w+32) for BOTH Q (e=w) and K (e=16+w), both
// groups -> 4 f32x16 accumulators. Scores computed from accumulators in
// registers (no Q/K LDS round-trip). V eliminated algebraically:
//   out = P@V = (P@x)@Wv^T + bv   (softmax rows sum to 1)
__global__ __launch_bounds__(1024, 4) void fused_attn_kernel(
    const float* __restrict__ x, const unsigned short* __restrict__ Wb,
    const float* __restrict__ bq, const float* __restrict__ bk,
    const float* __restrict__ bv, float* __restrict__ out)
{
    __shared__ unsigned short lds_x[2][RR * QSTR];  // 66,560 B (x, later y, bf16)
    __shared__ float lds_s[2][64];                  // scores -> probs, per group

    const int tid = threadIdx.x;
    const int lane = tid & 63;
    const int wave = tid >> 6;       // 0..15
    const int arow = lane & 31;
    const int ahalf = lane >> 5;     // 0/1 -> k-offset 0/8, row-offset +4

    const int gi0 = blockIdx.x << 1;     // group index = t*16+n; even, same t
    const int t = gi0 >> 4;
    const int n0 = gi0 & 15;

    // ---- W fragment pointers; first prefetches issued early (land while staging)
    const unsigned short* wq = Wb + ((long)wave << 14) + (lane << 3);
    const unsigned short* wk = wq + (16L << 14);
    bf16x8 pq[2], pk[2];
    pq[0] = *(const bf16x8*)(wq);
    pk[0] = *(const bf16x8*)(wk);
    pq[1] = *(const bf16x8*)(wq + 512);
    pk[1] = *(const bf16x8*)(wk + 512);

    if (tid < 128) lds_s[tid >> 6][tid & 63] = 0.f;

    // ---- Phase 1: stage x rows (g,b,m) -> bf16 LDS, coalesced float4 loads ----
    #pragma unroll
    for (int i = 0; i < 8; ++i) {
        int fi = i * 1024 + tid;     // float4 index, 8192 total (2 groups)
        int g = fi >> 12;
        int rem = fi & 4095;
        int row = rem >> 7;          // 0..31  (= b*8 + m)
        int d = (rem & 127) << 2;
        int b = row >> 3, m = row & 7;
        float4 v = *(const float4*)(x + ((((long)(b * Tt + t)) * Nn + (n0 + g)) * Mm + m) * Dd + d);
        ushort4 o;
        o.x = f2bf(v.x); o.y = f2bf(v.y); o.z = f2bf(v.z); o.w = f2bf(v.w);
        *(ushort4*)(&lds_x[g][row * QSTR + d]) = o;
    }
    __syncthreads();

    // ---- Phase 2: Q,K accumulators via mfma_f32_32x32x16_bf16 ----
    // A[row=lane&31][k=(lane>>5)*8+j]; D: col=lane&31, row=(r&3)+8*(r>>2)+4*(lane>>5)
    const unsigned short* abase0 = &lds_x[0][arow * QSTR + (ahalf << 3)];
    const unsigned short* abase1 = &lds_x[1][arow * QSTR + (ahalf << 3)];

    f32x16 aQ0, aQ1, aK0, aK1;
    #pragma unroll
    for (int r = 0; r < 16; ++r) { aQ0[r] = 0.f; aQ1[r] = 0.f; aK0[r] = 0.f; aK1[r] = 0.f; }

    #pragma unroll
    for (int kk = 0; kk < 32; ++kk) {
        int cur = kk & 1;
        bf16x8 wqf = pq[cur];
        bf16x8 wkf = pk[cur];
        if (kk < 30) {
            pq[cur] = *(const bf16x8*)(wq + (kk + 2) * 512);
            pk[cur] = *(const bf16x8*)(wk + (kk + 2) * 512);
        }
        bf16x8 a0 = *(const bf16x8*)(abase0 + kk * 16);
        bf16x8 a1 = *(const bf16x8*)(abase1 + kk * 16);
        aQ0 = __builtin_amdgcn_mfma_f32_32x32x16_bf16(a0, wqf, aQ0, 0, 0, 0);
        aK0 = __builtin_amdgcn_mfma_f32_32x32x16_bf16(a0, wkf, aK0, 0, 0, 0);
        aQ1 = __builtin_amdgcn_mfma_f32_32x32x16_bf16(a1, wqf, aQ1, 0, 0, 0);
        aK1 = __builtin_amdgcn_mfma_f32_32x32x16_bf16(a1, wkf, aK1, 0, 0, 0);
    }
    {
        int f = (wave << 5) + arow;
        float bqv = bq[f], bkv = bk[f];
        #pragma unroll
        for (int r = 0; r < 16; ++r) {
            aQ0[r] += bqv; aQ1[r] += bqv;
            aK0[r] += bkv; aK1[r] += bkv;
        }
    }

    // ---- Phase 3: scores from accumulators, in-register ----
    // Lane (h=lane>>5, f=lane&31) holds Q[8b+4h+j][F], K[8b+4h+j][F] at r=b*4+j
    // (F = 32*wave + f). Cross-half K via shfl_xor 32; reduce over the 32 f-lanes
    // of each half with a fold (send-half) butterfly; atomicAdd into lds_s.
    auto scores = [&](const f32x16& aQ, const f32x16& aK, int g) {
        float ksw[16];
        #pragma unroll
        for (int r = 0; r < 16; ++r) ksw[r] = __shfl_xor(aK[r], 32);
        #pragma unroll
        for (int j = 0; j < 4; ++j) {
            float v0 = 0.f, v1 = 0.f, v2 = 0.f, v3 = 0.f;
            float v4 = 0.f, v5 = 0.f, v6 = 0.f, v7 = 0.f;
            #pragma unroll
            for (int b = 0; b < 4; ++b) {
                float qv = aQ[b * 4 + j];
                v0 += qv * aK[b * 4 + 0];  v1 += qv * aK[b * 4 + 1];
                v2 += qv * aK[b * 4 + 2];  v3 += qv * aK[b * 4 + 3];
                v4 += qv * ksw[b * 4 + 0]; v5 += qv * ksw[b * 4 + 1];
                v6 += qv * ksw[b * 4 + 2]; v7 += qv * ksw[b * 4 + 3];
            }
            // fold reduction over f (32 lanes per half); after 3 folds lane bits
            // (b0,b1,b2) select slot = b0*4 + b1*2 + b2, then plain reduce 8,16.
            const bool s0 = (lane & 1) != 0;
            const bool s1 = (lane & 2) != 0;
            const bool s2 = (lane & 4) != 0;
            float n0v = (s0 ? v4 : v0) + __shfl_xor(s0 ? v0 : v4, 1);
            float n1v = (s0 ? v5 : v1) + __shfl_xor(s0 ? v1 : v5, 1);
            float n2v = (s0 ? v6 : v2) + __shfl_xor(s0 ? v2 : v6, 1);
            float n3v = (s0 ? v7 : v3) + __shfl_xor(s0 ? v3 : v7, 1);
            float m0v = (s1 ? n2v : n0v) + __shfl_xor(s1 ? n0v : n2v, 2);
            float m1v = (s1 ? n3v : n1v) + __shfl_xor(s1 ? n1v : n3v, 2);
            float u   = (s2 ? m1v : m0v) + __shfl_xor(s2 ? m0v : m1v, 4);
            u += __shfl_xor(u, 8);
            u += __shfl_xor(u, 16);
            int l5 = lane & 31;
            if (l5 < 8) {
                int slot = (l5 & 1) * 4 + (l5 & 2) + ((l5 >> 2) & 1);
                int m = 4 * ahalf + j;
                int k = (slot < 4) ? (4 * ahalf + slot) : (4 * (1 - ahalf) + (slot - 4));
                atomicAdd(&lds_s[g][m * 8 + k], u);
            }
        }
    };
    scores(aQ0, aK0, 0);
    scores(aQ1, aK1, 1);

    // early Wv prefetch: lands while softmax + P@x run
    const unsigned short* wv = Wb + ((32L + wave) << 14) + (lane << 3);
    bf16x8 pv[4];
    #pragma unroll
    for (int i = 0; i < 4; ++i) pv[i] = *(const bf16x8*)(wv + i * 512);

    __syncthreads();

    // ---- Phase 4: softmax over k (8) per (g,m) — 128 threads + shfl ----
    if (tid < 128) {
        int g = tid >> 6;
        int p = tid & 63;          // m = p>>3, k = p&7; 8-lane groups aligned
        float s = lds_s[g][p] * 0.04419417382415922f;   // 1/sqrt(512)
        float mx = s;
        mx = fmaxf(mx, __shfl_xor(mx, 1));
        mx = fmaxf(mx, __shfl_xor(mx, 2));
        mx = fmaxf(mx, __shfl_xor(mx, 4));
        float e = __expf(s - mx);
        float sum = e;
        sum += __shfl_xor(sum, 1);
        sum += __shfl_xor(sum, 2);
        sum += __shfl_xor(sum, 4);
        lds_s[g][p] = e / sum;
    }
    __syncthreads();

    // ---- Phase 5: y = P @ x, in place in lds_x (column-disjoint per thread) ----
    {
        int d4 = tid & 127;        // float4 group: d = d4*4
        int b = (tid >> 7) & 3;
        int g = tid >> 9;
        unsigned short* xr = &lds_x[g][(b << 3) * QSTR + (d4 << 2)];
        float4 xv[8];
        #pragma unroll
        for (int k = 0; k < 8; ++k) {
            ushort4 u = *(const ushort4*)(xr + k * QSTR);
            xv[k].x = bf2f(u.x); xv[k].y = bf2f(u.y);
            xv[k].z = bf2f(u.z); xv[k].w = bf2f(u.w);
        }
        ushort4 yr[8];
        #pragma unroll
        for (int m = 0; m < 8; ++m) {
            float4 o = {0.f, 0.f, 0.f, 0.f};
            #pragma unroll
            for (int k = 0; k < 8; ++k) {
                float w = lds_s[g][(m << 3) + k];
                o.x += w * xv[k].x; o.y += w * xv[k].y;
                o.z += w * xv[k].z; o.w += w * xv[k].w;
            }
            ushort4 oy;
            oy.x = f2bf(o.x); oy.y = f2bf(o.y); oy.z = f2bf(o.z); oy.w = f2bf(o.w);
            yr[m] = oy;
        }
        #pragma unroll
        for (int m = 0; m < 8; ++m) *(ushort4*)(xr + m * QSTR) = yr[m];
    }
    __syncthreads();

    // ---- Phase 6: out = y @ Wv^T + bv, accumulators -> global directly ----
    {
        f32x16 aV0, aV1;
        #pragma unroll
        for (int r = 0; r < 16; ++r) { aV0[r] = 0.f; aV1[r] = 0.f; }
        #pragma unroll
        for (int kk = 0; kk < 32; ++kk) {
            int cur = kk & 3;
            bf16x8 wvf = pv[cur];
            if (kk < 28) pv[cur] = *(const bf16x8*)(wv + (kk + 4) * 512);
            bf16x8 a0 = *(const bf16x8*)(abase0 + kk * 16);
            bf16x8 a1 = *(const bf16x8*)(abase1 + kk * 16);
            aV0 = __builtin_amdgcn_mfma_f32_32x32x16_bf16(a0, wvf, aV0, 0, 0, 0);
            aV1 = __builtin_amdgcn_mfma_f32_32x32x16_bf16(a1, wvf, aV1, 0, 0, 0);
        }
        int f = (wave << 5) + arow;
        float bvv = bv[f];
        float* o0 = out + f;
        #pragma unroll
        for (int r = 0; r < 16; ++r) {
            int mrow = (r & 3) + 8 * (r >> 2) + 4 * ahalf;
            int b = mrow >> 3, m = mrow & 7;
            long base = ((((long)(b * Tt + t)) * Nn + n0) * Mm + m) * Dd;
            o0[base] = aV0[r] + bvv;
            o0[base + (long)Mm * Dd] = aV1[r] + bvv;   // n0+1
        }
    }
}

extern "C" void kernel_launch(void* const* d_in, const int* in_sizes, int n_in,
                              void* d_out, int out_size, void* d_ws, size_t ws_size,
                              hipStream_t stream) {
    const float* x  = (const float*)d_in[0];
    const float* Wq = (const float*)d_in[1];
    const float* bq = (const float*)d_in[2];
    const float* Wk = (const float*)d_in[3];
    const float* bk = (const float*)d_in[4];
    const float* Wv = (const float*)d_in[5];
    const float* bv = (const float*)d_in[6];
    float* out = (float*)d_out;
    unsigned short* Wb = (unsigned short*)d_ws;   // 1.5 MiB, 32x32 fragment order

    convert_w_kernel<<<768, 256, 0, stream>>>(Wq, Wk, Wv, Wb);
    fused_attn_kernel<<<Tt * Nn / 2, 1024, 0, stream>>>(x, Wb, bq, bk, bv, out);
}